// Round 1
// baseline (146.204 us; speedup 1.0000x reference)
//
#include <hip/hip_runtime.h>

// Bahdanau multi-head attention, fp32, B=2 L=128 D=512 H=8 dh=64.
// Stage 1: Q/K/V = X @ W^T           (tiled GEMM, z-batched)
// Stage 2: qf/kf = head-split(Q/K) @ Wqa/Wka^T  (tiled GEMM, gathered rows)
// Stage 3: fused additive-score + masked softmax + PV (dominant: 134M tanh)
// Stage 4: out = inter @ Wo^T

#define NHEADS 8
#define DH 64
#define DM 512
#define BB 2
#define LQL 128
#define LKL 128
#define QPB 4   // queries per block in attn kernel (amortizes kf reads)

static __device__ __forceinline__ float fexp2(float x) { return __builtin_amdgcn_exp2f(x); }
static __device__ __forceinline__ float frcp(float x)  { return __builtin_amdgcn_rcpf(x); }

// ---------------- Stage 1: QKV projection, C = A (256x512) @ W(512x512)^T ----
__global__ __launch_bounds__(1024) void qkv_gemm_kernel(
    const float* __restrict__ q_in, const float* __restrict__ k_in, const float* __restrict__ v_in,
    const float* __restrict__ Wq, const float* __restrict__ Wk, const float* __restrict__ Wv,
    float* __restrict__ Q, float* __restrict__ K, float* __restrict__ V)
{
    const float* A; const float* W; float* C;
    if (blockIdx.z == 0)      { A = q_in; W = Wq; C = Q; }
    else if (blockIdx.z == 1) { A = k_in; W = Wk; C = K; }
    else                      { A = v_in; W = Wv; C = V; }
    __shared__ float As[32][33];
    __shared__ float Ws[32][33];
    const int tx = threadIdx.x, ty = threadIdx.y;
    const int row = blockIdx.y * 32 + ty;
    const int col = blockIdx.x * 32 + tx;
    float acc = 0.f;
    for (int k0 = 0; k0 < DM; k0 += 32) {
        As[ty][tx] = A[row * DM + k0 + tx];
        Ws[ty][tx] = W[(blockIdx.x * 32 + ty) * DM + k0 + tx];
        __syncthreads();
        #pragma unroll
        for (int kk = 0; kk < 32; ++kk) acc += As[ty][kk] * Ws[tx][kk];
        __syncthreads();
    }
    C[row * DM + col] = acc;
}

// ---------------- Stage 2: qf/kf = gathered-head-rows (2048x64) @ Wa(512x64)^T
__global__ __launch_bounds__(1024) void feat_gemm_kernel(
    const float* __restrict__ Q, const float* __restrict__ K,
    const float* __restrict__ Wqa, const float* __restrict__ Wka,
    float* __restrict__ qf, float* __restrict__ kf)
{
    const float* A = blockIdx.z ? K : Q;
    const float* W = blockIdx.z ? Wka : Wqa;
    float* C = blockIdx.z ? kf : qf;
    __shared__ float As[32][33];
    __shared__ float Ws[32][33];
    const int tx = threadIdx.x, ty = threadIdx.y;
    const int r = blockIdx.y * 32 + ty;      // row in (b,h,l)-flattened [0,2048)
    const int b  = r >> 10;
    const int hh = (r >> 7) & 7;
    const int l  = r & 127;
    float acc = 0.f;
    #pragma unroll
    for (int k0 = 0; k0 < DH; k0 += 32) {
        As[ty][tx] = A[(b * LQL + l) * DM + hh * DH + k0 + tx];
        Ws[ty][tx] = W[(blockIdx.x * 32 + ty) * DH + k0 + tx];
        __syncthreads();
        #pragma unroll
        for (int kk = 0; kk < 32; ++kk) acc += As[ty][kk] * Ws[tx][kk];
        __syncthreads();
    }
    C[(size_t)r * DM + blockIdx.x * 32 + tx] = acc;
}

// ---------------- Stage 3: fused additive score + masked softmax + PV --------
// Block: 256 threads = 4 waves, handles QPB=4 query rows of one (b,h).
// Wave w computes scores for k in [w*32, w*32+32) for all 4 q-rows;
// lane owns f-slice [lane*8, lane*8+8).
// score(q,k) = sum_f wv[f]*tanh(qf+kf) = sum_f wv[f] - 2*sum_f wv[f]*rcp(exp(2x)+1)
__global__ __launch_bounds__(256) void attn_kernel(
    const float* __restrict__ qf, const float* __restrict__ kf,
    const float* __restrict__ V, const float* __restrict__ wv_a,
    const int* __restrict__ valid_lens, float* __restrict__ inter)
{
    const int bx = blockIdx.x;                 // [0, B*H*LQ/QPB) = 512
    const int qt = bx & (LQL / QPB - 1);       // 0..31
    const int h  = (bx >> 5) & (NHEADS - 1);
    const int b  = bx >> 8;
    const int qbase = qt * QPB;
    const int tid = threadIdx.x;
    const int wave = tid >> 6;
    const int lane = tid & 63;

    __shared__ float s_score[QPB][LKL];
    __shared__ float s_attn[QPB][LKL];

    const float TWO_LOG2E = 2.8853900818f;     // 2*log2(e): exp(2x) = exp2(x*2log2e)
    const float LOG2E = 1.4426950409f;

    float qv[QPB][8], wvs[8];
    float wv0 = 0.f;
    {
        const float4* w4 = (const float4*)(wv_a + lane * 8);
        float4 wa = w4[0], wb = w4[1];
        float wtmp[8] = {wa.x, wa.y, wa.z, wa.w, wb.x, wb.y, wb.z, wb.w};
        #pragma unroll
        for (int j = 0; j < 8; ++j) { wv0 += wtmp[j]; wvs[j] = -2.f * wtmp[j]; }
        const float* qfb = qf + ((size_t)((b * NHEADS + h) * LQL + qbase)) * DM + lane * 8;
        #pragma unroll
        for (int i = 0; i < QPB; ++i) {
            const float4* q4 = (const float4*)(qfb + (size_t)i * DM);
            float4 qa = q4[0], qb = q4[1];
            qv[i][0] = qa.x * TWO_LOG2E; qv[i][1] = qa.y * TWO_LOG2E;
            qv[i][2] = qa.z * TWO_LOG2E; qv[i][3] = qa.w * TWO_LOG2E;
            qv[i][4] = qb.x * TWO_LOG2E; qv[i][5] = qb.y * TWO_LOG2E;
            qv[i][6] = qb.z * TWO_LOG2E; qv[i][7] = qb.w * TWO_LOG2E;
        }
    }

    const float* kfb = kf + ((size_t)(b * NHEADS + h) * LKL) * DM + lane * 8;
    for (int kk = 0; kk < LKL / 4; ++kk) {
        const int k = wave * (LKL / 4) + kk;
        const float4* k4 = (const float4*)(kfb + (size_t)k * DM);
        float4 ka = k4[0], kb2 = k4[1];
        float kv[8] = {ka.x, ka.y, ka.z, ka.w, kb2.x, kb2.y, kb2.z, kb2.w};
        float acc[QPB];
        #pragma unroll
        for (int i = 0; i < QPB; ++i) acc[i] = wv0;
        #pragma unroll
        for (int j = 0; j < 8; ++j) {
            const float kx = kv[j] * TWO_LOG2E;
            #pragma unroll
            for (int i = 0; i < QPB; ++i) {
                float e = fexp2(qv[i][j] + kx);     // exp(2x); +inf/0 at extremes -> tanh = +/-1
                float r = frcp(e + 1.f);
                acc[i] += wvs[j] * r;
            }
        }
        #pragma unroll
        for (int i = 0; i < QPB; ++i) {
            float a = acc[i];
            #pragma unroll
            for (int off = 32; off; off >>= 1) a += __shfl_xor(a, off, 64);
            if (lane == 0) s_score[i][k] = a;
        }
    }
    __syncthreads();

    // masked softmax: wave w handles q-row w (lane covers k=lane, k=lane+64)
    const int Lv = valid_lens[b];
    {
        const int w = wave;
        float v0 = (lane < Lv)      ? s_score[w][lane]      : -3.0e38f;
        float v1 = (lane + 64 < Lv) ? s_score[w][lane + 64] : -3.0e38f;
        float m = fmaxf(v0, v1);
        #pragma unroll
        for (int off = 32; off; off >>= 1) m = fmaxf(m, __shfl_xor(m, off, 64));
        float e0 = fexp2((v0 - m) * LOG2E);  // masked lanes underflow to exactly 0
        float e1 = fexp2((v1 - m) * LOG2E);
        float s = e0 + e1;
        #pragma unroll
        for (int off = 32; off; off >>= 1) s += __shfl_xor(s, off, 64);
        float inv = frcp(s);
        s_attn[w][lane] = e0 * inv;
        s_attn[w][lane + 64] = e1 * inv;
    }
    __syncthreads();

    // PV: thread t -> (q-row = t>>6, d = t&63); V slab (32KB) is L1/L2-hot
    const int qr = tid >> 6;
    const int d = tid & 63;
    const float* vb = V + ((size_t)b * LKL) * DM + h * DH + d;
    float acc = 0.f;
    #pragma unroll 4
    for (int k = 0; k < LKL; ++k) acc += s_attn[qr][k] * vb[(size_t)k * DM];
    inter[((size_t)(b * LQL + qbase + qr)) * DM + h * DH + d] = acc;
}

// ---------------- Stage 4: out = inter (256x512) @ Wo(512x512)^T -------------
__global__ __launch_bounds__(1024) void out_gemm_kernel(
    const float* __restrict__ A, const float* __restrict__ Wo, float* __restrict__ C)
{
    __shared__ float As[32][33];
    __shared__ float Ws[32][33];
    const int tx = threadIdx.x, ty = threadIdx.y;
    const int row = blockIdx.y * 32 + ty;
    const int col = blockIdx.x * 32 + tx;
    float acc = 0.f;
    for (int k0 = 0; k0 < DM; k0 += 32) {
        As[ty][tx] = A[row * DM + k0 + tx];
        Ws[ty][tx] = Wo[(blockIdx.x * 32 + ty) * DM + k0 + tx];
        __syncthreads();
        #pragma unroll
        for (int kk = 0; kk < 32; ++kk) acc += As[ty][kk] * Ws[tx][kk];
        __syncthreads();
    }
    C[row * DM + col] = acc;
}

extern "C" void kernel_launch(void* const* d_in, const int* in_sizes, int n_in,
                              void* d_out, int out_size, void* d_ws, size_t ws_size,
                              hipStream_t stream)
{
    const float* queries = (const float*)d_in[0];
    const float* keys    = (const float*)d_in[1];
    const float* values  = (const float*)d_in[2];
    const int*   vlens   = (const int*)d_in[3];
    const float* Wq   = (const float*)d_in[4];
    const float* Wk   = (const float*)d_in[5];
    const float* Wv   = (const float*)d_in[6];
    const float* Wo   = (const float*)d_in[7];
    const float* Wqa  = (const float*)d_in[8];
    const float* Wka  = (const float*)d_in[9];
    const float* wv_a = (const float*)d_in[10];
    float* out = (float*)d_out;
    float* ws = (float*)d_ws;

    // ws layout (floats): Q[131072] K[131072] V[131072] qf[1048576] kf[1048576] inter[131072]
    float* Q     = ws;
    float* K     = ws + 131072;
    float* V     = ws + 262144;
    float* qf    = ws + 393216;
    float* kf    = ws + 393216 + 1048576;
    float* inter = ws + 393216 + 2097152;

    qkv_gemm_kernel<<<dim3(16, 8, 3), dim3(32, 32), 0, stream>>>(
        queries, keys, values, Wq, Wk, Wv, Q, K, V);
    feat_gemm_kernel<<<dim3(16, 64, 2), dim3(32, 32), 0, stream>>>(
        Q, K, Wqa, Wka, qf, kf);
    attn_kernel<<<dim3(BB * NHEADS * (LQL / QPB)), dim3(256), 0, stream>>>(
        qf, kf, V, wv_a, vlens, inter);
    out_gemm_kernel<<<dim3(16, 8), dim3(32, 32), 0, stream>>>(inter, Wo, out);
}

// Round 2
// 91.580 us; speedup vs baseline: 1.5965x; 1.5965x over previous
//
#include <hip/hip_runtime.h>

// Bahdanau multi-head attention, fp32, B=2 L=128 D=512 H=8 dh=64.
// R1: attn = per-thread (k, f-quarter) partials, no shuffles in score phase,
//     valid_len wave-skip; GEMMs = 64x32 tile, 4x2 micro.

#define NHEADS 8
#define DH 64
#define DM 512
#define BB 2
#define LQL 128
#define LKL 128
#define QPB 4

static __device__ __forceinline__ float fexp2(float x) { return __builtin_amdgcn_exp2f(x); }
static __device__ __forceinline__ float frcp(float x)  { return __builtin_amdgcn_rcpf(x); }

// ---------- shared tiled-GEMM body: C[M,N] = A[M,K] @ W[N,K]^T --------------
// BM=64, BN=32, BK=16, 256 threads, 4x2 micro-tile per thread.
template<int KDIM, bool GATHER>
__device__ __forceinline__ void gemm_tile(const float* __restrict__ A,
                                          const float* __restrict__ W,
                                          float* __restrict__ C,
                                          int bm0, int bn0, int N)
{
    __shared__ float As[16][68];   // [k][m], pad: stride 68 -> <=2-way on write
    __shared__ float Ws[16][36];   // [k][n]
    const int tid = threadIdx.x;
    const int tm = tid >> 4;       // 0..15 -> rows tm*4..tm*4+3
    const int tn = tid & 15;       // 0..15 -> cols tn*2..tn*2+1

    const int arow_l = tid >> 2;               // local A row 0..63
    const int akq    = (tid & 3) * 4;          // k-offset 0/4/8/12
    size_t abase;
    if (GATHER) {
        const int r = bm0 + arow_l;            // (b,h,l)-flattened row
        const int b = r >> 10, hh = (r >> 7) & 7, l = r & 127;
        abase = (size_t)(b * LQL + l) * DM + hh * DH;
    } else {
        abase = (size_t)(bm0 + arow_l) * KDIM;
    }
    const int wrow = bn0 + (tid >> 3);         // n index (32 rows per tile)
    const int wkq  = (tid & 7) * 2;            // k-offset 0..14 even

    float c[4][2] = {};
    for (int k0 = 0; k0 < KDIM; k0 += 16) {
        const float4 av = *(const float4*)(A + abase + k0 + akq);
        const float2 wv = *(const float2*)(W + (size_t)wrow * KDIM + k0 + wkq);
        __syncthreads();                       // previous iter finished reading
        As[akq + 0][arow_l] = av.x;
        As[akq + 1][arow_l] = av.y;
        As[akq + 2][arow_l] = av.z;
        As[akq + 3][arow_l] = av.w;
        Ws[wkq + 0][tid >> 3] = wv.x;
        Ws[wkq + 1][tid >> 3] = wv.y;
        __syncthreads();
        #pragma unroll
        for (int kk = 0; kk < 16; ++kk) {
            const float4 a4 = *(const float4*)&As[kk][tm * 4];
            const float2 w2 = *(const float2*)&Ws[kk][tn * 2];
            c[0][0] += a4.x * w2.x; c[0][1] += a4.x * w2.y;
            c[1][0] += a4.y * w2.x; c[1][1] += a4.y * w2.y;
            c[2][0] += a4.z * w2.x; c[2][1] += a4.z * w2.y;
            c[3][0] += a4.w * w2.x; c[3][1] += a4.w * w2.y;
        }
    }
    #pragma unroll
    for (int i = 0; i < 4; ++i) {
        float2 o; o.x = c[i][0]; o.y = c[i][1];
        *(float2*)(C + (size_t)(bm0 + tm * 4 + i) * N + bn0 + tn * 2) = o;
    }
}

// ---------------- Stage 1: QKV projections (z in {Q,K,V}) -------------------
__global__ __launch_bounds__(256) void qkv_gemm_kernel(
    const float* __restrict__ q_in, const float* __restrict__ k_in, const float* __restrict__ v_in,
    const float* __restrict__ Wq, const float* __restrict__ Wk, const float* __restrict__ Wv,
    float* __restrict__ Q, float* __restrict__ K, float* __restrict__ V)
{
    const float* A; const float* W; float* C;
    if (blockIdx.z == 0)      { A = q_in; W = Wq; C = Q; }
    else if (blockIdx.z == 1) { A = k_in; W = Wk; C = K; }
    else                      { A = v_in; W = Wv; C = V; }
    gemm_tile<DM, false>(A, W, C, blockIdx.y * 64, blockIdx.x * 32, DM);
}

// ---------------- Stage 2: qf/kf features (gathered head rows) --------------
__global__ __launch_bounds__(256) void feat_gemm_kernel(
    const float* __restrict__ Q, const float* __restrict__ K,
    const float* __restrict__ Wqa, const float* __restrict__ Wka,
    float* __restrict__ qf, float* __restrict__ kf)
{
    const float* A = blockIdx.z ? K : Q;
    const float* W = blockIdx.z ? Wka : Wqa;
    float* C = blockIdx.z ? kf : qf;
    gemm_tile<DH, true>(A, W, C, blockIdx.y * 64, blockIdx.x * 32, DM);
}

// ---------------- Stage 3: fused score + masked softmax + PV ----------------
// Block: 512 threads, one (b,h) + 4 q-rows. Thread t: k = t&127, f-quarter = t>>7.
// No cross-lane ops in score phase; partials combined via LDS.
// softmax shift-invariance: sum_f wv[f] constant dropped.
__global__ __launch_bounds__(512, 2) void attn_kernel(
    const float* __restrict__ qf, const float* __restrict__ kf,
    const float* __restrict__ V, const float* __restrict__ wv_a,
    const int* __restrict__ valid_lens, float* __restrict__ inter)
{
    const int bx = blockIdx.x;                 // 512 blocks
    const int qt = bx & 31;
    const int h  = (bx >> 5) & 7;
    const int b  = bx >> 8;
    const int qbase = qt * QPB;
    const int bh = b * NHEADS + h;
    const int t = threadIdx.x;

    __shared__ float s_qf2[QPB][DM];           // qf * 2log2e
    __shared__ float s_wv2[DM];                // wv * -2
    __shared__ float s_part[4][QPB][LKL];      // per-f-quarter partial scores
    __shared__ float s_attn[QPB][LKL];
    __shared__ float s_pv[2][QPB][DH];

    const float C2 = 2.8853900818f;            // 2*log2(e)
    const float LOG2E = 1.4426950409f;

    // stage qf (pre-scaled) and wv (pre-scaled by -2)
    {
        const int r = t >> 7, c = (t & 127) * 4;
        const float4 v = *(const float4*)(qf + ((size_t)bh * LQL + qbase + r) * DM + c);
        s_qf2[r][c]     = v.x * C2;
        s_qf2[r][c + 1] = v.y * C2;
        s_qf2[r][c + 2] = v.z * C2;
        s_qf2[r][c + 3] = v.w * C2;
        s_wv2[t] = wv_a[t] * -2.0f;
    }
    __syncthreads();

    const int k  = t & 127;
    const int fq = t >> 7;
    const int fbase = fq * 128;
    const int Lv = valid_lens[b];

    float acc[QPB] = {0.f, 0.f, 0.f, 0.f};
    if (k < Lv) {                              // wave-skip fully-masked k ranges
        const float* kp = kf + ((size_t)bh * LKL + k) * DM + fbase;
        float4 kA = *(const float4*)kp;
        float4 kB = *(const float4*)(kp + 4);
        #pragma unroll 1
        for (int it = 0; it < 16; ++it) {
            float4 nA, nB;
            if (it < 15) {                     // prefetch next f-chunk
                nA = *(const float4*)(kp + 8);
                nB = *(const float4*)(kp + 12);
            } else { nA = kA; nB = kB; }
            const int f0 = fbase + it * 8;
            const float4 w0 = *(const float4*)&s_wv2[f0];
            const float4 w1 = *(const float4*)&s_wv2[f0 + 4];
            #pragma unroll
            for (int q = 0; q < QPB; ++q) {
                const float4 q0 = *(const float4*)&s_qf2[q][f0];
                const float4 q1 = *(const float4*)&s_qf2[q][f0 + 4];
                float a = acc[q];
                a = fmaf(w0.x, frcp(fexp2(fmaf(kA.x, C2, q0.x)) + 1.f), a);
                a = fmaf(w0.y, frcp(fexp2(fmaf(kA.y, C2, q0.y)) + 1.f), a);
                a = fmaf(w0.z, frcp(fexp2(fmaf(kA.z, C2, q0.z)) + 1.f), a);
                a = fmaf(w0.w, frcp(fexp2(fmaf(kA.w, C2, q0.w)) + 1.f), a);
                a = fmaf(w1.x, frcp(fexp2(fmaf(kB.x, C2, q1.x)) + 1.f), a);
                a = fmaf(w1.y, frcp(fexp2(fmaf(kB.y, C2, q1.y)) + 1.f), a);
                a = fmaf(w1.z, frcp(fexp2(fmaf(kB.z, C2, q1.z)) + 1.f), a);
                a = fmaf(w1.w, frcp(fexp2(fmaf(kB.w, C2, q1.w)) + 1.f), a);
                acc[q] = a;
            }
            kA = nA; kB = nB; kp += 8;
        }
    }
    s_part[fq][0][k] = acc[0];
    s_part[fq][1][k] = acc[1];
    s_part[fq][2][k] = acc[2];
    s_part[fq][3][k] = acc[3];
    __syncthreads();

    // reduce 4 partials + masked softmax: wave w = q-row, lane covers k, k+64
    if (t < 256) {
        const int q = t >> 6, lane = t & 63;
        float v0 = -3.0e38f, v1 = -3.0e38f;
        if (lane < Lv)
            v0 = s_part[0][q][lane] + s_part[1][q][lane]
               + s_part[2][q][lane] + s_part[3][q][lane];
        if (lane + 64 < Lv)
            v1 = s_part[0][q][lane + 64] + s_part[1][q][lane + 64]
               + s_part[2][q][lane + 64] + s_part[3][q][lane + 64];
        float m = fmaxf(v0, v1);
        #pragma unroll
        for (int off = 32; off; off >>= 1) m = fmaxf(m, __shfl_xor(m, off, 64));
        const float e0 = fexp2((v0 - m) * LOG2E);   // masked -> exp2(-inf) = 0
        const float e1 = fexp2((v1 - m) * LOG2E);
        float s = e0 + e1;
        #pragma unroll
        for (int off = 32; off; off >>= 1) s += __shfl_xor(s, off, 64);
        const float inv = frcp(s);
        s_attn[q][lane]      = e0 * inv;
        s_attn[q][lane + 64] = e1 * inv;
    }
    __syncthreads();

    // PV: t -> (kh = t>>8, q = (t>>6)&3, d = t&63); only k < Lv contribute
    {
        const int d = t & 63, q = (t >> 6) & 3, kh = t >> 8;
        const float* vb = V + ((size_t)(b * LKL + kh * 64)) * DM + h * DH + d;
        int kmax = Lv - kh * 64;
        kmax = kmax < 0 ? 0 : (kmax > 64 ? 64 : kmax);
        float a = 0.f;
        #pragma unroll 4
        for (int kk = 0; kk < kmax; ++kk)
            a += s_attn[q][kh * 64 + kk] * vb[(size_t)kk * DM];
        s_pv[kh][q][d] = a;
    }
    __syncthreads();
    if (t < 256) {
        const int q = t >> 6, d = t & 63;
        inter[((size_t)(b * LQL + qbase + q)) * DM + h * DH + d] =
            s_pv[0][q][d] + s_pv[1][q][d];
    }
}

// ---------------- Stage 4: out = inter @ Wo^T -------------------------------
__global__ __launch_bounds__(256) void out_gemm_kernel(
    const float* __restrict__ A, const float* __restrict__ Wo, float* __restrict__ C)
{
    gemm_tile<DM, false>(A, Wo, C, blockIdx.y * 64, blockIdx.x * 32, DM);
}

extern "C" void kernel_launch(void* const* d_in, const int* in_sizes, int n_in,
                              void* d_out, int out_size, void* d_ws, size_t ws_size,
                              hipStream_t stream)
{
    const float* queries = (const float*)d_in[0];
    const float* keys    = (const float*)d_in[1];
    const float* values  = (const float*)d_in[2];
    const int*   vlens   = (const int*)d_in[3];
    const float* Wq   = (const float*)d_in[4];
    const float* Wk   = (const float*)d_in[5];
    const float* Wv   = (const float*)d_in[6];
    const float* Wo   = (const float*)d_in[7];
    const float* Wqa  = (const float*)d_in[8];
    const float* Wka  = (const float*)d_in[9];
    const float* wv_a = (const float*)d_in[10];
    float* out = (float*)d_out;
    float* ws = (float*)d_ws;

    // ws layout (floats): Q[131072] K[131072] V[131072] qf[1048576] kf[1048576] inter[131072]
    float* Q     = ws;
    float* K     = ws + 131072;
    float* V     = ws + 262144;
    float* qf    = ws + 393216;
    float* kf    = ws + 393216 + 1048576;
    float* inter = ws + 393216 + 2097152;

    qkv_gemm_kernel<<<dim3(16, 4, 3), dim3(256), 0, stream>>>(
        queries, keys, values, Wq, Wk, Wv, Q, K, V);
    feat_gemm_kernel<<<dim3(16, 32, 2), dim3(256), 0, stream>>>(
        Q, K, Wqa, Wka, qf, kf);
    attn_kernel<<<dim3(BB * NHEADS * (LQL / QPB)), dim3(512), 0, stream>>>(
        qf, kf, V, wv_a, vlens, inter);
    out_gemm_kernel<<<dim3(16, 4), dim3(256), 0, stream>>>(inter, Wo, out);
}